// Round 5
// baseline (81.317 us; speedup 1.0000x reference)
//
#include <hip/hip_runtime.h>

// CapsuleLayer: bf16 MFMA, persistent 4-row blocks, A-frags in registers,
// B rows in a 4-slot LDS ring staged via global_load_lds.
// Sizes: B=8, C=128, H=W=32, K=3, pad=1 -> oh=ow=32, NC=512, 3 routing iters.
//
// d_ws: wT bf16 [9][512][128] (k-contig) ; inT bf16 [8][34][34][128] padded+swizzled.
// Swizzle: within each 256B channel-block of padded cell w, byte ^= (w&7)<<4.

typedef __bf16 bf16x8 __attribute__((ext_vector_type(8)));
typedef float  f32x4  __attribute__((ext_vector_type(4)));

#define NC    512
#define CIN   128
#define HW    32
#define INT_H 34
#define INT_W 34
#define ROWB  (INT_W * 256)          // 8704 B per padded row
#define WT_ELEMS (9 * NC * CIN)

// ---- fused prepass: blocks [0,288) -> wT ; [288, 866) -> inT (incl. borders) ----
__global__ __launch_bounds__(256)
void prepass(const float* __restrict__ in, const float* __restrict__ wgt,
             __bf16* __restrict__ wT, __bf16* __restrict__ inT) {
    const int t = threadIdx.x;
    if (blockIdx.x < 288) {
        int g   = blockIdx.x * 256 + t;     // 73728
        int n   = g & 511;
        int cb  = (g >> 9) & 15;
        int tap = g >> 13;
        bf16x8 v;
        #pragma unroll
        for (int k = 0; k < 8; k++)
            v[k] = (__bf16)wgt[(tap * CIN + cb * 8 + k) * NC + n];
        *(bf16x8*)(wT + ((size_t)tap * NC + n) * CIN + cb * 8) = v;
    } else {
        int g    = (blockIdx.x - 288) * 256 + t;   // 147968 = 8*34*34*16
        int cb   = g & 15;
        int cell = g >> 4;
        int w    = cell % INT_W;
        int rest = cell / INT_W;
        int h    = rest % INT_H;
        int b    = rest / INT_H;
        bf16x8 v;
        #pragma unroll
        for (int k = 0; k < 8; k++) v[k] = (__bf16)0.0f;
        if (h >= 1 && h <= 32 && w >= 1 && w <= 32) {
            #pragma unroll
            for (int k = 0; k < 8; k++)
                v[k] = (__bf16)in[((b * CIN + cb * 8 + k) * HW + (h - 1)) * HW + (w - 1)];
        }
        int within = (cb * 16) ^ ((w & 7) << 4);
        *(bf16x8*)((char*)inT + (size_t)(b * INT_H + h) * ROWB + w * 256 + within) = v;
    }
}

// ---- main ----
__global__ __launch_bounds__(256, 2)
void caps_main(const __bf16* __restrict__ wT, const __bf16* __restrict__ inT,
               const float* __restrict__ bias, float* __restrict__ out) {
    __shared__ __attribute__((aligned(16))) unsigned char ring[4 * ROWB];  // 34816 B

    const int x    = blockIdx.x;          // 512 blocks
    const int nblk = x & 7;
    const int hg   = (x >> 3) & 7;
    const int b    = x >> 6;
    const int h0   = hg * 4;              // first output row (= first padded row needed)
    const int t    = threadIdx.x;
    const int lane = t & 63;
    const int wm   = t >> 6;
    const int l15  = lane & 15;
    const int l4   = lane >> 4;
    const int nb   = nblk * 64 + wm * 16;

    const char* ibase = (const char*)inT + (size_t)(b * INT_H) * ROWB;

    // stage one padded row into a ring slot (8704 B = 8x1KB + 512B tail)
    auto stage_row = [&](int row, int slot) {
        const char* src = ibase + (size_t)row * ROWB;
        unsigned char* dst = ring + slot * ROWB;
        int c = wm * 2;
        __builtin_amdgcn_global_load_lds((const unsigned*)(src + c * 1024 + lane * 16),
                                         (unsigned*)(dst + c * 1024), 16, 0, 0);
        __builtin_amdgcn_global_load_lds((const unsigned*)(src + (c + 1) * 1024 + lane * 16),
                                         (unsigned*)(dst + (c + 1) * 1024), 16, 0, 0);
        if (wm == 3 && lane < 32)
            __builtin_amdgcn_global_load_lds((const unsigned*)(src + 8192 + lane * 16),
                                             (unsigned*)(dst + 8192), 16, 0, 0);
    };

    // ---- A prologue: 36 frags resident in registers for the whole block ----
    bf16x8 afrag[9][4];
    {
        const __bf16* aptr = wT + (size_t)(nb + l15) * CIN + l4 * 8;
        #pragma unroll
        for (int tap = 0; tap < 9; tap++)
            #pragma unroll
            for (int kk = 0; kk < 4; kk++)
                afrag[tap][kk] = *(const bf16x8*)(aptr + (size_t)(tap * NC) * CIN + kk * 32);
    }

    // prologue staging: padded rows h0..h0+2 -> slots 0..2
    stage_row(h0 + 0, 0);
    stage_row(h0 + 1, 1);
    stage_row(h0 + 2, 2);

    for (int r = 0; r < 4; ++r) {
        __syncthreads();                       // drains stages (and prior reads)
        if (r < 3) stage_row(h0 + r + 3, (r + 3) & 3);

        // ---- GEMM for output row hr = h0 + r, window slots (r+i)&3 ----
        f32x4 acc[9][2];
        #pragma unroll
        for (int tap = 0; tap < 9; tap++) {
            f32x4 bv = *(const f32x4*)(bias + tap * NC + nb + l4 * 4);
            acc[tap][0] = bv;
            acc[tap][1] = bv;
        }
        #pragma unroll
        for (int i = 0; i < 3; i++) {
            const unsigned char* rowp = ring + ((r + i) & 3) * ROWB;
            #pragma unroll
            for (int j = 0; j < 3; j++) {
                const int tap = i * 3 + j;
                #pragma unroll
                for (int kk = 0; kk < 4; kk++) {
                    #pragma unroll
                    for (int nf = 0; nf < 2; nf++) {
                        int pos = j + nf * 16 + l15;
                        int off = pos * 256 + ((kk * 64 + l4 * 16) ^ ((pos & 7) << 4));
                        bf16x8 bv = *(const bf16x8*)(rowp + off);
                        acc[tap][nf] =
                            __builtin_amdgcn_mfma_f32_16x16x32_bf16(afrag[tap][kk], bv,
                                                                    acc[tap][nf], 0, 0, 0);
                    }
                }
            }
        }

        // ---- routing ----
        f32x4 o[2];
        #pragma unroll
        for (int nf = 0; nf < 2; nf++) {
            f32x4 s = acc[0][nf];
            #pragma unroll
            for (int tap = 1; tap < 9; tap++) s += acc[tap][nf];
            o[nf] = s * (1.0f / 9.0f);
        }
        #pragma unroll
        for (int it = 0; it < 3; it++) {
            #pragma unroll
            for (int nf = 0; nf < 2; nf++) {
                float cw[9];
                float S = 0.f;
                #pragma unroll
                for (int tap = 0; tap < 9; tap++) {
                    f32x4 d = o[nf] - acc[tap][nf];
                    float d2 = d[0] * d[0] + d[1] * d[1] + d[2] * d[2] + d[3] * d[3];
                    d2 += __shfl_xor(d2, 16);
                    d2 += __shfl_xor(d2, 32);
                    float rr = __builtin_amdgcn_rsqf(d2 + 1e-4f);
                    cw[tap] = rr;
                    S += rr;
                }
                float inv = __builtin_amdgcn_rcpf(S);
                f32x4 on = acc[0][nf] * cw[0];
                #pragma unroll
                for (int tap = 1; tap < 9; tap++) on += acc[tap][nf] * cw[tap];
                o[nf] = on * inv;
            }
        }

        // ---- store: out[b][n][hr][w] ----
        const int hr = h0 + r;
        size_t obase = ((size_t)(b * NC + nb + l4 * 4) * HW + hr) * HW + l15;
        #pragma unroll
        for (int nf = 0; nf < 2; nf++)
            #pragma unroll
            for (int reg = 0; reg < 4; reg++)
                out[obase + (size_t)reg * HW * HW + nf * 16] = o[nf][reg];
    }
}

extern "C" void kernel_launch(void* const* d_in, const int* in_sizes, int n_in,
                              void* d_out, int out_size, void* d_ws, size_t ws_size,
                              hipStream_t stream) {
    const float* in   = (const float*)d_in[0];
    const float* wgt  = (const float*)d_in[1];
    const float* bias = (const float*)d_in[2];
    float* out = (float*)d_out;

    __bf16* wT  = (__bf16*)d_ws;
    __bf16* inT = wT + WT_ELEMS;

    prepass<<<866, 256, 0, stream>>>(in, wgt, wT, inT);

    caps_main<<<512, 256, 0, stream>>>(wT, inT, bias, out);
}

// Round 6
// 59.970 us; speedup vs baseline: 1.3560x; 1.3560x over previous
//
#include <hip/hip_runtime.h>

// CapsuleLayer: bf16 MFMA, persistent 4-row blocks, A-frags in registers,
// B rows in a 4-slot LDS ring staged via global_load_lds.
// nf-split: the two 16-position halves of each row are processed sequentially
// so only acc[9] (36 VGPR) is live at a time -> no spill with afrag[9][4] (144).
// Sizes: B=8, C=128, H=W=32, K=3, pad=1 -> oh=ow=32, NC=512, 3 routing iters.
//
// d_ws: wT bf16 [9][512][128] (k-contig) ; inT bf16 [8][34][34][128] padded+swizzled.
// Swizzle: within each 256B channel-block of padded cell w, byte ^= (w&15)<<4.

typedef __bf16 bf16x8 __attribute__((ext_vector_type(8)));
typedef float  f32x4  __attribute__((ext_vector_type(4)));

#define NC    512
#define CIN   128
#define HW    32
#define INT_H 34
#define INT_W 34
#define ROWB  (INT_W * 256)          // 8704 B per padded row
#define WT_ELEMS (9 * NC * CIN)

// ---- fused prepass: blocks [0,288) -> wT ; [288, 866) -> inT (incl. borders) ----
__global__ __launch_bounds__(256)
void prepass(const float* __restrict__ in, const float* __restrict__ wgt,
             __bf16* __restrict__ wT, __bf16* __restrict__ inT) {
    const int t = threadIdx.x;
    if (blockIdx.x < 288) {
        int g   = blockIdx.x * 256 + t;     // 73728
        int n   = g & 511;
        int cb  = (g >> 9) & 15;
        int tap = g >> 13;
        bf16x8 v;
        #pragma unroll
        for (int k = 0; k < 8; k++)
            v[k] = (__bf16)wgt[(tap * CIN + cb * 8 + k) * NC + n];
        *(bf16x8*)(wT + ((size_t)tap * NC + n) * CIN + cb * 8) = v;
    } else {
        int g    = (blockIdx.x - 288) * 256 + t;   // 147968 = 8*34*34*16
        int cb   = g & 15;
        int cell = g >> 4;
        int w    = cell % INT_W;
        int rest = cell / INT_W;
        int h    = rest % INT_H;
        int b    = rest / INT_H;
        bf16x8 v;
        #pragma unroll
        for (int k = 0; k < 8; k++) v[k] = (__bf16)0.0f;
        if (h >= 1 && h <= 32 && w >= 1 && w <= 32) {
            #pragma unroll
            for (int k = 0; k < 8; k++)
                v[k] = (__bf16)in[((b * CIN + cb * 8 + k) * HW + (h - 1)) * HW + (w - 1)];
        }
        int within = (cb * 16) ^ ((w & 15) << 4);
        *(bf16x8*)((char*)inT + (size_t)(b * INT_H + h) * ROWB + w * 256 + within) = v;
    }
}

// ---- main ----
__global__ __launch_bounds__(256, 2)
void caps_main(const __bf16* __restrict__ wT, const __bf16* __restrict__ inT,
               const float* __restrict__ bias, float* __restrict__ out) {
    __shared__ __attribute__((aligned(16))) unsigned char ring[4 * ROWB];  // 34816 B

    const int x    = blockIdx.x;          // 512 blocks
    const int nblk = x & 7;
    const int hg   = (x >> 3) & 7;
    const int b    = x >> 6;
    const int h0   = hg * 4;              // first output row (= first padded row needed)
    const int t    = threadIdx.x;
    const int lane = t & 63;
    const int wm   = t >> 6;
    const int l15  = lane & 15;
    const int l4   = lane >> 4;
    const int nb   = nblk * 64 + wm * 16;

    const char* ibase = (const char*)inT + (size_t)(b * INT_H) * ROWB;

    // stage one padded row into a ring slot (8704 B = 8x1KB + 512B tail)
    auto stage_row = [&](int row, int slot) {
        const char* src = ibase + (size_t)row * ROWB;
        unsigned char* dst = ring + slot * ROWB;
        int c = wm * 2;
        __builtin_amdgcn_global_load_lds((const unsigned*)(src + c * 1024 + lane * 16),
                                         (unsigned*)(dst + c * 1024), 16, 0, 0);
        __builtin_amdgcn_global_load_lds((const unsigned*)(src + (c + 1) * 1024 + lane * 16),
                                         (unsigned*)(dst + (c + 1) * 1024), 16, 0, 0);
        if (wm == 3 && lane < 32)
            __builtin_amdgcn_global_load_lds((const unsigned*)(src + 8192 + lane * 16),
                                             (unsigned*)(dst + 8192), 16, 0, 0);
    };

    // ---- A prologue: 36 frags resident in registers for the whole block ----
    bf16x8 afrag[9][4];
    {
        const __bf16* aptr = wT + (size_t)(nb + l15) * CIN + l4 * 8;
        #pragma unroll
        for (int tap = 0; tap < 9; tap++)
            #pragma unroll
            for (int kk = 0; kk < 4; kk++)
                afrag[tap][kk] = *(const bf16x8*)(aptr + (size_t)(tap * NC) * CIN + kk * 32);
    }

    // prologue staging: padded rows h0..h0+2 -> slots 0..2
    stage_row(h0 + 0, 0);
    stage_row(h0 + 1, 1);
    stage_row(h0 + 2, 2);

    for (int r = 0; r < 4; ++r) {
        __syncthreads();                       // drains stages (and prior reads)
        if (r < 3) stage_row(h0 + r + 3, (r + 3) & 3);

        // ---- two independent 16-position half-rows, processed sequentially ----
        #pragma unroll 1
        for (int nf = 0; nf < 2; ++nf) {
            f32x4 acc[9];
            #pragma unroll
            for (int tap = 0; tap < 9; tap++)
                acc[tap] = *(const f32x4*)(bias + tap * NC + nb + l4 * 4);

            #pragma unroll
            for (int i = 0; i < 3; i++) {
                const unsigned char* rowp = ring + ((r + i) & 3) * ROWB;
                #pragma unroll
                for (int j = 0; j < 3; j++) {
                    const int tap = i * 3 + j;
                    #pragma unroll
                    for (int kk = 0; kk < 4; kk++) {
                        int pos = j + nf * 16 + l15;
                        int off = pos * 256 + ((kk * 64 + l4 * 16) ^ ((pos & 15) << 4));
                        bf16x8 bv = *(const bf16x8*)(rowp + off);
                        acc[tap] =
                            __builtin_amdgcn_mfma_f32_16x16x32_bf16(afrag[tap][kk], bv,
                                                                    acc[tap], 0, 0, 0);
                    }
                }
            }

            // ---- routing (16 positions) ----
            f32x4 o = acc[0];
            #pragma unroll
            for (int tap = 1; tap < 9; tap++) o += acc[tap];
            o = o * (1.0f / 9.0f);

            #pragma unroll
            for (int it = 0; it < 3; it++) {
                float cw[9];
                float S = 0.f;
                #pragma unroll
                for (int tap = 0; tap < 9; tap++) {
                    f32x4 d = o - acc[tap];
                    float d2 = d[0] * d[0] + d[1] * d[1] + d[2] * d[2] + d[3] * d[3];
                    d2 += __shfl_xor(d2, 16);
                    d2 += __shfl_xor(d2, 32);
                    float rr = __builtin_amdgcn_rsqf(d2 + 1e-4f);
                    cw[tap] = rr;
                    S += rr;
                }
                float inv = __builtin_amdgcn_rcpf(S);
                f32x4 on = acc[0] * cw[0];
                #pragma unroll
                for (int tap = 1; tap < 9; tap++) on += acc[tap] * cw[tap];
                o = on * inv;
            }

            // ---- store: out[b][n][hr][w], n = nb + l4*4 + reg, w = nf*16 + l15 ----
            const int hr = h0 + r;
            size_t obase = ((size_t)(b * NC + nb + l4 * 4) * HW + hr) * HW + nf * 16 + l15;
            #pragma unroll
            for (int reg = 0; reg < 4; reg++)
                out[obase + (size_t)reg * HW * HW] = o[reg];
        }
    }
}

extern "C" void kernel_launch(void* const* d_in, const int* in_sizes, int n_in,
                              void* d_out, int out_size, void* d_ws, size_t ws_size,
                              hipStream_t stream) {
    const float* in   = (const float*)d_in[0];
    const float* wgt  = (const float*)d_in[1];
    const float* bias = (const float*)d_in[2];
    float* out = (float*)d_out;

    __bf16* wT  = (__bf16*)d_ws;
    __bf16* inT = wT + WT_ELEMS;

    prepass<<<866, 256, 0, stream>>>(in, wgt, wT, inT);

    caps_main<<<512, 256, 0, stream>>>(wT, inT, bias, out);
}